// Round 13
// baseline (9244.934 us; speedup 1.0000x reference)
//
#include <hip/hip_runtime.h>
#include <math.h>

#define NN 4096
#define DD 256
#define NCLS 64
#define EPSF 2.2204460492503131e-16f
#define NITER 48
#define KMAX 64
#define TASK 32                      // nnz per wave-task
#define NNZ_CAP (NN * 2 * KMAX)
#define MAXTASK (NNZ_CAP / TASK)
#define LDP 40                       // padded LDS row (halves): 80B stride

typedef __attribute__((ext_vector_type(8))) _Float16 half8;
typedef __attribute__((ext_vector_type(4))) float f32x4;

// ---- prep: e = emb/(sigma+eps)^2, split into f16 hi/lo, sq = rowsum(e*e) ----
__global__ void k_prep(const float* __restrict__ emb, const float* __restrict__ sig,
                       _Float16* __restrict__ ehi, _Float16* __restrict__ elo,
                       float* __restrict__ sq) {
  int row = blockIdx.x, t = threadIdx.x;  // block = 256 = DD
  float s = sig[row] + EPSF;
  float v = emb[row * DD + t];
  v = v / s; v = v / s;
  _Float16 h = (_Float16)v;
  _Float16 l = (_Float16)(v - (float)h);
  ehi[row * DD + t] = h;
  elo[row * DD + t] = l;
  __shared__ float red[DD];
  red[t] = v * v; __syncthreads();
  for (int off = 128; off > 0; off >>= 1) {
    if (t < off) red[t] += red[t + off];
    __syncthreads();
  }
  if (t == 0) sq[row] = red[0];
}

// ---- dense W = exp(-dist/2) via f16 split MFMA: G = e e^T (C = A.B^T) ------
__global__ __launch_bounds__(256) void k_gemmw(
    const _Float16* __restrict__ ehi, const _Float16* __restrict__ elo,
    const float* __restrict__ sq, float* __restrict__ W) {
  __shared__ _Float16 Ah[128][LDP];
  __shared__ _Float16 Al[128][LDP];
  __shared__ _Float16 Bh[128][LDP];
  __shared__ _Float16 Bl[128][LDP];
  int t = threadIdx.x;
  int lane = t & 63, wv = t >> 6;
  int wm = wv >> 1, wn = wv & 1;
  int rowbase = blockIdx.y * 128, colbase = blockIdx.x * 128;
  f32x4 acc[4][4];
#pragma unroll
  for (int m = 0; m < 4; ++m)
#pragma unroll
    for (int n = 0; n < 4; ++n) acc[m][n] = (f32x4){0.f, 0.f, 0.f, 0.f};
  int fr = lane & 15, kc = (lane >> 4) * 8;
  for (int k0 = 0; k0 < DD; k0 += 32) {
    for (int q = t; q < 512; q += 256) {
      int lr = q >> 2, ls = (q & 3) * 8;
      size_t ga = (size_t)(rowbase + lr) * DD + k0 + ls;
      size_t gb = (size_t)(colbase + lr) * DD + k0 + ls;
      *(uint4*)&Ah[lr][ls] = *(const uint4*)&ehi[ga];
      *(uint4*)&Al[lr][ls] = *(const uint4*)&elo[ga];
      *(uint4*)&Bh[lr][ls] = *(const uint4*)&ehi[gb];
      *(uint4*)&Bl[lr][ls] = *(const uint4*)&elo[gb];
    }
    __syncthreads();
    half8 ah[4], al[4], bh[4], bl[4];
#pragma unroll
    for (int m = 0; m < 4; ++m) {
      ah[m] = *(const half8*)&Ah[wm * 64 + m * 16 + fr][kc];
      al[m] = *(const half8*)&Al[wm * 64 + m * 16 + fr][kc];
    }
#pragma unroll
    for (int n = 0; n < 4; ++n) {
      bh[n] = *(const half8*)&Bh[wn * 64 + n * 16 + fr][kc];
      bl[n] = *(const half8*)&Bl[wn * 64 + n * 16 + fr][kc];
    }
#pragma unroll
    for (int m = 0; m < 4; ++m)
#pragma unroll
      for (int n = 0; n < 4; ++n) {
        acc[m][n] = __builtin_amdgcn_mfma_f32_16x16x32_f16(ah[m], bh[n], acc[m][n], 0, 0, 0);
        acc[m][n] = __builtin_amdgcn_mfma_f32_16x16x32_f16(ah[m], bl[n], acc[m][n], 0, 0, 0);
        acc[m][n] = __builtin_amdgcn_mfma_f32_16x16x32_f16(al[m], bh[n], acc[m][n], 0, 0, 0);
      }
    __syncthreads();
  }
#pragma unroll
  for (int m = 0; m < 4; ++m) {
#pragma unroll
    for (int reg = 0; reg < 4; ++reg) {
      int i = rowbase + wm * 64 + m * 16 + (lane >> 4) * 4 + reg;
      float sqi = sq[i];
#pragma unroll
      for (int n = 0; n < 4; ++n) {
        int j = colbase + wn * 64 + n * 16 + (lane & 15);
        float dist = (sqi + sq[j] - 2.0f * acc[m][n][reg]) * (1.0f / DD);
        W[(size_t)i * NN + j] = expf(-0.5f * dist);
      }
    }
  }
}

// ---------------- zero a u32 buffer ----------------
__global__ void k_zero(unsigned* __restrict__ p, int n) {
  int i = blockIdx.x * blockDim.x + threadIdx.x;
  if (i < n) p[i] = 0u;
}

// ---- per-row top-k (R8 proven): 4 waves x 1024 elems, 16/lane --------------
// ties: higher value wins; equal value -> lower column (matches jax top_k).
__global__ __launch_bounds__(256) void k_topk(const float* __restrict__ W,
                                              int* __restrict__ idx,
                                              const int* __restrict__ kptr) {
  int row = blockIdx.x;
  int t = threadIdx.x, lane = t & 63, w = t >> 6;
  int K = kptr[0]; if (K > KMAX) K = KMAX;
  const float* Wr = &W[(size_t)row * NN];
  float val[16];
#pragma unroll
  for (int i = 0; i < 16; ++i) val[i] = Wr[w * 1024 + i * 64 + lane];
  unsigned rm = 0;
  __shared__ float lv[4][KMAX];
  __shared__ int   lc[4][KMAX];
  for (int k = 0; k < K; ++k) {
    float vb = -1e38f; int cb = 0x7fffffff;
#pragma unroll
    for (int i = 0; i < 16; ++i) {
      bool ok = !((rm >> i) & 1u);
      if (ok && val[i] > vb) { vb = val[i]; cb = w * 1024 + i * 64 + lane; }
    }
    for (int off = 32; off > 0; off >>= 1) {
      float ov = __shfl_xor(vb, off, 64);
      int   oc = __shfl_xor(cb, off, 64);
      if (ov > vb || (ov == vb && oc < cb)) { vb = ov; cb = oc; }
    }
    if ((cb & 63) == lane) { int i = (cb >> 6) & 15; rm |= 1u << i; }
    if (lane == 0) { lv[w][k] = vb; lc[w][k] = cb; }
  }
  __syncthreads();
  if (w == 0) {
    float cv[4]; int cc[4]; unsigned crm = 0;
#pragma unroll
    for (int j = 0; j < 4; ++j) {
      if (lane < K) { cv[j] = lv[j][lane]; cc[j] = lc[j][lane]; }
      else { cv[j] = -1e38f; cc[j] = 0x7fffffff; }
    }
    for (int k = 0; k < K; ++k) {
      float vb = -1e38f; int cb = 0x7fffffff;
#pragma unroll
      for (int j = 0; j < 4; ++j) {
        bool ok = !((crm >> j) & 1u);
        if (ok && (cv[j] > vb || (cv[j] == vb && cc[j] < cb))) { vb = cv[j]; cb = cc[j]; }
      }
      for (int off = 32; off > 0; off >>= 1) {
        float ov = __shfl_xor(vb, off, 64);
        int   oc = __shfl_xor(cb, off, 64);
        if (ov > vb || (ov == vb && oc < cb)) { vb = ov; cb = oc; }
      }
#pragma unroll
      for (int j = 0; j < 4; ++j) if (cc[j] == cb) crm |= 1u << j;
      if (lane == 0) idx[row * KMAX + k] = cb;
    }
  }
}

// ---------------- scatter symmetric bitmask ----------------
__global__ void k_scatter(const int* __restrict__ idx, unsigned* __restrict__ mask,
                          const int* __restrict__ kptr) {
  int K = kptr[0]; if (K > KMAX) K = KMAX;
  int tid = blockIdx.x * blockDim.x + threadIdx.x;
  if (tid >= NN * K) return;
  int i = tid / K, k = tid % K;
  int j = idx[i * KMAX + k];
  atomicOr(&mask[i * 128 + (j >> 5)], 1u << (j & 31));
  atomicOr(&mask[j * 128 + (i >> 5)], 1u << (i & 31));
}

// ---------------- degree (sum of masked W per row) + Dinv ------------
__global__ void k_degree(const unsigned* __restrict__ mask, const float* __restrict__ W,
                         float* __restrict__ Dinv, int* __restrict__ deg) {
  int row = blockIdx.x, t = threadIdx.x;  // block = 128
  unsigned m = mask[row * 128 + t];
  float dsum = 0.f; int cnt = __popc(m);
  unsigned mm = m;
  while (mm) {
    int b = __ffs(mm) - 1; mm &= mm - 1;
    dsum += W[(size_t)row * NN + t * 32 + b];
  }
  __shared__ float rs[128];
  __shared__ int   rc[128];
  rs[t] = dsum; rc[t] = cnt; __syncthreads();
  for (int off = 64; off > 0; off >>= 1) {
    if (t < off) { rs[t] += rs[t + off]; rc[t] += rc[t + off]; }
    __syncthreads();
  }
  if (t == 0) { deg[row] = rc[0]; Dinv[row] = sqrtf(1.0f / (rs[0] + EPSF)); }
}

// ------- exclusive scan of deg -> rowptr (one block, shuffle scan) ----------
__global__ void k_scan(const int* __restrict__ deg, int* __restrict__ rowptr) {
  int t = threadIdx.x;
  int lane = t & 63, w = t >> 6;
  int loc[16]; int s = 0;
  for (int u = 0; u < 16; ++u) { loc[u] = s; s += deg[t * 16 + u]; }
  int tot = s, inc = s;
  for (int off = 1; off < 64; off <<= 1) {
    int n = __shfl_up(inc, off, 64);
    if (lane >= off) inc += n;
  }
  __shared__ int wt[4];
  if (lane == 63) wt[w] = inc;
  __syncthreads();
  int base = 0;
  for (int u = 0; u < w; ++u) base += wt[u];
  int excl = base + inc - tot;
  for (int u = 0; u < 16; ++u) rowptr[t * 16 + u] = excl + loc[u];
  if (t == 255) rowptr[NN] = excl + tot;
}

// ---------------- fill CSR of alpha*S, packed (col, val) --------------------
__global__ void k_fill(const unsigned* __restrict__ mask, const float* __restrict__ W,
                       const float* __restrict__ Dinv, const int* __restrict__ rowptr,
                       int2* __restrict__ cv, const float* __restrict__ alphap) {
  int row = blockIdx.x, t = threadIdx.x;  // block = 128
  float alpha = alphap[0];
  unsigned m = mask[row * 128 + t];
  __shared__ int wcnt[128];
  wcnt[t] = __popc(m); __syncthreads();
  int pre = 0;
  for (int u = 0; u < t; ++u) pre += wcnt[u];
  int base = rowptr[row] + pre;
  float di = Dinv[row];
  while (m) {
    int b = __ffs(m) - 1; m &= m - 1;
    int j = t * 32 + b;
    float v = alpha * W[(size_t)row * NN + j] * di * Dinv[j];
    cv[base] = make_int2(j, __float_as_int(v));
    ++base;
  }
}

// ------- taskrow (binary search once) + per-row task counts (need) ----------
__global__ void k_taskrow(const int* __restrict__ rowptr, int* __restrict__ taskrow) {
  int task = blockIdx.x * blockDim.x + threadIdx.x;
  int nnz = rowptr[NN];
  int ntask = (nnz + TASK - 1) / TASK;
  if (task >= ntask) return;
  int start = task * TASK;
  int lo = 0, hi = NN;
  while (hi - lo > 1) {
    int mid = (lo + hi) >> 1;
    if (rowptr[mid] <= start) lo = mid; else hi = mid;
  }
  taskrow[task] = lo;
}

__global__ void k_need(const int* __restrict__ rowptr, int* __restrict__ need) {
  int r = blockIdx.x * blockDim.x + threadIdx.x;
  if (r >= NN) return;
  int p0 = rowptr[r], p1 = rowptr[r + 1];
  need[r] = (p1 - 1) / TASK - p0 / TASK + 1;   // rows are never empty (diag)
}

// ---- init: X=0, R=D0=B; SV0=0, CNT0=0 --------------------------------------
__global__ __launch_bounds__(256) void k_init_state(
    const int* __restrict__ labels, int Ns, float* __restrict__ X,
    float* __restrict__ R, float* __restrict__ D0, float* __restrict__ SV0,
    int* __restrict__ CNT0) {
  int idx = blockIdx.x * 256 + threadIdx.x;     // NN*64 total
  int i = idx >> 6, c = idx & 63;
  float b = (i < Ns && labels[i] == c) ? 1.0f : 0.0f;
  X[idx] = 0.0f; R[idx] = b; D0[idx] = b; SV0[idx] = 0.0f;
  if (idx < NN) CNT0[idx] = 0;
}

// ---- fused iteration: SpMM + counter-gated per-row Chebyshev update --------
// One dispatch per iteration. Wave finishing the last task of row r (cnt hits
// need[r]) performs row r's update; SV read via atomicAdd(,0) = coherent RMW.
__global__ __launch_bounds__(256) void k_iter(
    const int* __restrict__ rowptr, const int2* __restrict__ cv,
    const int* __restrict__ taskrow, const int* __restrict__ need,
    float* __restrict__ X, float* __restrict__ R,
    const float* __restrict__ Dc, float* __restrict__ Dn,
    float* __restrict__ SVw, float* __restrict__ SVz,
    int* __restrict__ CNTw, int* __restrict__ CNTz,
    const float* __restrict__ alphap, int it) {
  float alpha = alphap[0];
  float sigma1 = 1.0f / alpha;
  float rho_prev = alpha;
  for (int k = 0; k < it; ++k) rho_prev = 1.0f / (2.0f * sigma1 - rho_prev);
  float rho = 1.0f / (2.0f * sigma1 - rho_prev);
  float c1 = rho * rho_prev, c2 = 2.0f * rho / alpha;

  int lane = threadIdx.x & 63;
  int wave0 = (blockIdx.x * 256 + threadIdx.x) >> 6;
  int nwaves = (gridDim.x * 256) >> 6;
  int nnz = rowptr[NN];
  int ntask = (nnz + TASK - 1) / TASK;
  for (int task = wave0; task < ntask; task += nwaves) {
    int start = task * TASK;
    int end = start + TASK; if (end > nnz) end = nnz;
    float prod[TASK];
#pragma unroll
    for (int u = 0; u < TASK; ++u) {
      int p = start + u;
      if (p < end) {
        int2 c = cv[p];
        prod[u] = __int_as_float(c.y) * Dc[(size_t)c.x * 64 + lane];
      } else prod[u] = 0.0f;
    }
    int r0 = taskrow[task];
    int r = r0;
    int rend = rowptr[r + 1];
    float acc = 0.0f;
#pragma unroll
    for (int u = 0; u < TASK; ++u) {
      int p = start + u;
      if (p >= end) break;
      while (p >= rend) {
        atomicAdd(&SVw[(size_t)r * 64 + lane], acc);
        acc = 0.0f; ++r; rend = rowptr[r + 1];
      }
      acc += prod[u];
    }
    atomicAdd(&SVw[(size_t)r * 64 + lane], acc);
    int rlast = r;
    __threadfence();                       // release SV adds before counting
    for (int rr = r0; rr <= rlast; ++rr) {
      int old;
      if (lane == 0) old = atomicAdd(&CNTw[rr], 1);
      old = __shfl(old, 0, 64);
      if (old + 1 == need[rr]) {           // this wave completes row rr
        __threadfence();
        size_t o = (size_t)rr * 64 + lane;
        float s = atomicAdd(&SVw[o], 0.0f);   // coherent read of full sum
        float d = Dc[o];
        float x = X[o] + d;
        float res = R[o] - (d - s);
        X[o] = x; R[o] = res;
        Dn[o] = c1 * d + c2 * res;
        SVz[o] = 0.0f;                     // prep buffers for iteration it+1
        if (lane == 0) CNTz[rr] = 0;
      }
    }
  }
}

// ---------------- host launch ----------------
static inline char* carve(char*& p, size_t bytes) {
  char* r = p;
  size_t a = (bytes + 255) & ~(size_t)255;
  p += a;
  return r;
}

extern "C" void kernel_launch(void* const* d_in, const int* in_sizes, int n_in,
                              void* d_out, int out_size, void* d_ws, size_t ws_size,
                              hipStream_t stream) {
  const float* emb    = (const float*)d_in[0];
  const float* sigma  = (const float*)d_in[1];
  const float* alphap = (const float*)d_in[2];
  const int*   labels = (const int*)d_in[3];
  const int*   kptr   = (const int*)d_in[4];
  int Ns = in_sizes[3];
  float* X = (float*)d_out;   // X state IS the output [NN][64]

  char* p = (char*)d_ws;
  _Float16* ehi    = (_Float16*)carve(p, (size_t)NN * DD * 2);
  _Float16* elo    = (_Float16*)carve(p, (size_t)NN * DD * 2);
  float*    sq     = (float*)carve(p, NN * 4);
  float*    Wm     = (float*)carve(p, (size_t)NN * NN * 4);
  int*      topk   = (int*)carve(p, NN * KMAX * 4);
  unsigned* mask   = (unsigned*)carve(p, NN * 128 * 4);
  float*    Dinv   = (float*)carve(p, NN * 4);
  int*      deg    = (int*)carve(p, NN * 4);
  int*      rowptr = (int*)carve(p, (NN + 1) * 4);
  int2*     cv     = (int2*)carve(p, (size_t)NNZ_CAP * 8);
  int*      trow   = (int*)carve(p, (size_t)MAXTASK * 4);
  int*      needb  = (int*)carve(p, NN * 4);
  float*    Rbuf   = (float*)carve(p, (size_t)NN * NCLS * 4);
  float*    Db0    = (float*)carve(p, (size_t)NN * NCLS * 4);
  float*    Db1    = (float*)carve(p, (size_t)NN * NCLS * 4);
  float*    SV0    = (float*)carve(p, (size_t)NN * NCLS * 4);
  float*    SV1    = (float*)carve(p, (size_t)NN * NCLS * 4);
  int*      CNT0   = (int*)carve(p, NN * 4);
  int*      CNT1   = (int*)carve(p, NN * 4);
  float*    SB[2]  = {SV0, SV1};
  int*      CB[2]  = {CNT0, CNT1};

  k_prep<<<NN, DD, 0, stream>>>(emb, sigma, ehi, elo, sq);
  k_gemmw<<<dim3(NN / 128, NN / 128), 256, 0, stream>>>(ehi, elo, sq, Wm);
  k_zero<<<(NN * 128 + 255) / 256, 256, 0, stream>>>(mask, NN * 128);
  k_topk<<<NN, 256, 0, stream>>>(Wm, topk, kptr);
  k_scatter<<<(NN * KMAX + 255) / 256, 256, 0, stream>>>(topk, mask, kptr);
  k_degree<<<NN, 128, 0, stream>>>(mask, Wm, Dinv, deg);
  k_scan<<<1, 256, 0, stream>>>(deg, rowptr);
  k_fill<<<NN, 128, 0, stream>>>(mask, Wm, Dinv, rowptr, cv, alphap);
  k_taskrow<<<(MAXTASK + 255) / 256, 256, 0, stream>>>(rowptr, trow);
  k_need<<<(NN + 255) / 256, 256, 0, stream>>>(rowptr, needb);

  k_init_state<<<(NN * NCLS) / 256, 256, 0, stream>>>(labels, Ns, X, Rbuf, Db0,
                                                      SB[0], CB[0]);
  for (int it = 0; it < NITER; ++it) {
    float* Dc = (it & 1) ? Db1 : Db0;
    float* Dn = (it & 1) ? Db0 : Db1;
    k_iter<<<640, 256, 0, stream>>>(rowptr, cv, trow, needb, X, Rbuf, Dc, Dn,
                                    SB[it & 1], SB[(it + 1) & 1],
                                    CB[it & 1], CB[(it + 1) & 1], alphap, it);
  }
}

// Round 14
// 1279.593 us; speedup vs baseline: 7.2249x; 7.2249x over previous
//
#include <hip/hip_runtime.h>
#include <math.h>

#define NN 4096
#define DD 256
#define NCLS 64
#define EPSF 2.2204460492503131e-16f
#define NITER 44
#define KMAX 64
#define TASK 32                      // nnz per wave-task
#define NNZ_CAP (NN * 2 * KMAX)
#define MAXTASK (NNZ_CAP / TASK)
#define LDP 40                       // padded LDS row (halves): 80B stride

typedef __attribute__((ext_vector_type(8))) _Float16 half8;
typedef __attribute__((ext_vector_type(4))) float f32x4;

// ---- prep: e = emb/(sigma+eps)^2, split into f16 hi/lo, sq = rowsum(e*e) ----
__global__ void k_prep(const float* __restrict__ emb, const float* __restrict__ sig,
                       _Float16* __restrict__ ehi, _Float16* __restrict__ elo,
                       float* __restrict__ sq) {
  int row = blockIdx.x, t = threadIdx.x;  // block = 256 = DD
  float s = sig[row] + EPSF;
  float v = emb[row * DD + t];
  v = v / s; v = v / s;
  _Float16 h = (_Float16)v;
  _Float16 l = (_Float16)(v - (float)h);
  ehi[row * DD + t] = h;
  elo[row * DD + t] = l;
  __shared__ float red[DD];
  red[t] = v * v; __syncthreads();
  for (int off = 128; off > 0; off >>= 1) {
    if (t < off) red[t] += red[t + off];
    __syncthreads();
  }
  if (t == 0) sq[row] = red[0];
}

// ---- dense W = exp(-dist/2) via f16 split MFMA: G = e e^T (C = A.B^T) ------
__global__ __launch_bounds__(256) void k_gemmw(
    const _Float16* __restrict__ ehi, const _Float16* __restrict__ elo,
    const float* __restrict__ sq, float* __restrict__ W) {
  __shared__ _Float16 Ah[128][LDP];
  __shared__ _Float16 Al[128][LDP];
  __shared__ _Float16 Bh[128][LDP];
  __shared__ _Float16 Bl[128][LDP];
  int t = threadIdx.x;
  int lane = t & 63, wv = t >> 6;
  int wm = wv >> 1, wn = wv & 1;
  int rowbase = blockIdx.y * 128, colbase = blockIdx.x * 128;
  f32x4 acc[4][4];
#pragma unroll
  for (int m = 0; m < 4; ++m)
#pragma unroll
    for (int n = 0; n < 4; ++n) acc[m][n] = (f32x4){0.f, 0.f, 0.f, 0.f};
  int fr = lane & 15, kc = (lane >> 4) * 8;
  for (int k0 = 0; k0 < DD; k0 += 32) {
    for (int q = t; q < 512; q += 256) {
      int lr = q >> 2, ls = (q & 3) * 8;
      size_t ga = (size_t)(rowbase + lr) * DD + k0 + ls;
      size_t gb = (size_t)(colbase + lr) * DD + k0 + ls;
      *(uint4*)&Ah[lr][ls] = *(const uint4*)&ehi[ga];
      *(uint4*)&Al[lr][ls] = *(const uint4*)&elo[ga];
      *(uint4*)&Bh[lr][ls] = *(const uint4*)&ehi[gb];
      *(uint4*)&Bl[lr][ls] = *(const uint4*)&elo[gb];
    }
    __syncthreads();
    half8 ah[4], al[4], bh[4], bl[4];
#pragma unroll
    for (int m = 0; m < 4; ++m) {
      ah[m] = *(const half8*)&Ah[wm * 64 + m * 16 + fr][kc];
      al[m] = *(const half8*)&Al[wm * 64 + m * 16 + fr][kc];
    }
#pragma unroll
    for (int n = 0; n < 4; ++n) {
      bh[n] = *(const half8*)&Bh[wn * 64 + n * 16 + fr][kc];
      bl[n] = *(const half8*)&Bl[wn * 64 + n * 16 + fr][kc];
    }
#pragma unroll
    for (int m = 0; m < 4; ++m)
#pragma unroll
      for (int n = 0; n < 4; ++n) {
        acc[m][n] = __builtin_amdgcn_mfma_f32_16x16x32_f16(ah[m], bh[n], acc[m][n], 0, 0, 0);
        acc[m][n] = __builtin_amdgcn_mfma_f32_16x16x32_f16(ah[m], bl[n], acc[m][n], 0, 0, 0);
        acc[m][n] = __builtin_amdgcn_mfma_f32_16x16x32_f16(al[m], bh[n], acc[m][n], 0, 0, 0);
      }
    __syncthreads();
  }
#pragma unroll
  for (int m = 0; m < 4; ++m) {
#pragma unroll
    for (int reg = 0; reg < 4; ++reg) {
      int i = rowbase + wm * 64 + m * 16 + (lane >> 4) * 4 + reg;
      float sqi = sq[i];
#pragma unroll
      for (int n = 0; n < 4; ++n) {
        int j = colbase + wn * 64 + n * 16 + (lane & 15);
        float dist = (sqi + sq[j] - 2.0f * acc[m][n][reg]) * (1.0f / DD);
        W[(size_t)i * NN + j] = expf(-0.5f * dist);
      }
    }
  }
}

// ---------------- zero a u32 buffer ----------------
__global__ void k_zero(unsigned* __restrict__ p, int n) {
  int i = blockIdx.x * blockDim.x + threadIdx.x;
  if (i < n) p[i] = 0u;
}

// ---- per-row top-k (R8 proven): 4 waves x 1024 elems, 16/lane --------------
// ties: higher value wins; equal value -> lower column (matches jax top_k).
__global__ __launch_bounds__(256) void k_topk(const float* __restrict__ W,
                                              int* __restrict__ idx,
                                              const int* __restrict__ kptr) {
  int row = blockIdx.x;
  int t = threadIdx.x, lane = t & 63, w = t >> 6;
  int K = kptr[0]; if (K > KMAX) K = KMAX;
  const float* Wr = &W[(size_t)row * NN];
  float val[16];
#pragma unroll
  for (int i = 0; i < 16; ++i) val[i] = Wr[w * 1024 + i * 64 + lane];
  unsigned rm = 0;
  __shared__ float lv[4][KMAX];
  __shared__ int   lc[4][KMAX];
  for (int k = 0; k < K; ++k) {
    float vb = -1e38f; int cb = 0x7fffffff;
#pragma unroll
    for (int i = 0; i < 16; ++i) {
      bool ok = !((rm >> i) & 1u);
      if (ok && val[i] > vb) { vb = val[i]; cb = w * 1024 + i * 64 + lane; }
    }
    for (int off = 32; off > 0; off >>= 1) {
      float ov = __shfl_xor(vb, off, 64);
      int   oc = __shfl_xor(cb, off, 64);
      if (ov > vb || (ov == vb && oc < cb)) { vb = ov; cb = oc; }
    }
    if ((cb & 63) == lane) { int i = (cb >> 6) & 15; rm |= 1u << i; }
    if (lane == 0) { lv[w][k] = vb; lc[w][k] = cb; }
  }
  __syncthreads();
  if (w == 0) {
    float cv[4]; int cc[4]; unsigned crm = 0;
#pragma unroll
    for (int j = 0; j < 4; ++j) {
      if (lane < K) { cv[j] = lv[j][lane]; cc[j] = lc[j][lane]; }
      else { cv[j] = -1e38f; cc[j] = 0x7fffffff; }
    }
    for (int k = 0; k < K; ++k) {
      float vb = -1e38f; int cb = 0x7fffffff;
#pragma unroll
      for (int j = 0; j < 4; ++j) {
        bool ok = !((crm >> j) & 1u);
        if (ok && (cv[j] > vb || (cv[j] == vb && cc[j] < cb))) { vb = cv[j]; cb = cc[j]; }
      }
      for (int off = 32; off > 0; off >>= 1) {
        float ov = __shfl_xor(vb, off, 64);
        int   oc = __shfl_xor(cb, off, 64);
        if (ov > vb || (ov == vb && oc < cb)) { vb = ov; cb = oc; }
      }
#pragma unroll
      for (int j = 0; j < 4; ++j) if (cc[j] == cb) crm |= 1u << j;
      if (lane == 0) idx[row * KMAX + k] = cb;
    }
  }
}

// ---------------- scatter symmetric bitmask ----------------
__global__ void k_scatter(const int* __restrict__ idx, unsigned* __restrict__ mask,
                          const int* __restrict__ kptr) {
  int K = kptr[0]; if (K > KMAX) K = KMAX;
  int tid = blockIdx.x * blockDim.x + threadIdx.x;
  if (tid >= NN * K) return;
  int i = tid / K, k = tid % K;
  int j = idx[i * KMAX + k];
  atomicOr(&mask[i * 128 + (j >> 5)], 1u << (j & 31));
  atomicOr(&mask[j * 128 + (i >> 5)], 1u << (i & 31));
}

// ---------------- degree (sum of masked W per row) + Dinv ------------
__global__ void k_degree(const unsigned* __restrict__ mask, const float* __restrict__ W,
                         float* __restrict__ Dinv, int* __restrict__ deg) {
  int row = blockIdx.x, t = threadIdx.x;  // block = 128
  unsigned m = mask[row * 128 + t];
  float dsum = 0.f; int cnt = __popc(m);
  unsigned mm = m;
  while (mm) {
    int b = __ffs(mm) - 1; mm &= mm - 1;
    dsum += W[(size_t)row * NN + t * 32 + b];
  }
  __shared__ float rs[128];
  __shared__ int   rc[128];
  rs[t] = dsum; rc[t] = cnt; __syncthreads();
  for (int off = 64; off > 0; off >>= 1) {
    if (t < off) { rs[t] += rs[t + off]; rc[t] += rc[t + off]; }
    __syncthreads();
  }
  if (t == 0) { deg[row] = rc[0]; Dinv[row] = sqrtf(1.0f / (rs[0] + EPSF)); }
}

// ------- exclusive scan of deg -> rowptr (one block, shuffle scan) ----------
__global__ void k_scan(const int* __restrict__ deg, int* __restrict__ rowptr) {
  int t = threadIdx.x;
  int lane = t & 63, w = t >> 6;
  int loc[16]; int s = 0;
  for (int u = 0; u < 16; ++u) { loc[u] = s; s += deg[t * 16 + u]; }
  int tot = s, inc = s;
  for (int off = 1; off < 64; off <<= 1) {
    int n = __shfl_up(inc, off, 64);
    if (lane >= off) inc += n;
  }
  __shared__ int wt[4];
  if (lane == 63) wt[w] = inc;
  __syncthreads();
  int base = 0;
  for (int u = 0; u < w; ++u) base += wt[u];
  int excl = base + inc - tot;
  for (int u = 0; u < 16; ++u) rowptr[t * 16 + u] = excl + loc[u];
  if (t == 255) rowptr[NN] = excl + tot;
}

// ---------------- fill CSR of alpha*S, packed (col, val) --------------------
__global__ void k_fill(const unsigned* __restrict__ mask, const float* __restrict__ W,
                       const float* __restrict__ Dinv, const int* __restrict__ rowptr,
                       int2* __restrict__ cv, const float* __restrict__ alphap) {
  int row = blockIdx.x, t = threadIdx.x;  // block = 128
  float alpha = alphap[0];
  unsigned m = mask[row * 128 + t];
  __shared__ int wcnt[128];
  wcnt[t] = __popc(m); __syncthreads();
  int pre = 0;
  for (int u = 0; u < t; ++u) pre += wcnt[u];
  int base = rowptr[row] + pre;
  float di = Dinv[row];
  while (m) {
    int b = __ffs(m) - 1; m &= m - 1;
    int j = t * 32 + b;
    float v = alpha * W[(size_t)row * NN + j] * di * Dinv[j];
    cv[base] = make_int2(j, __float_as_int(v));
    ++base;
  }
}

// ------- precompute task -> starting row ------
__global__ void k_taskrow(const int* __restrict__ rowptr, int* __restrict__ taskrow) {
  int task = blockIdx.x * blockDim.x + threadIdx.x;
  int nnz = rowptr[NN];
  int ntask = (nnz + TASK - 1) / TASK;
  if (task >= ntask) return;
  int start = task * TASK;
  int lo = 0, hi = NN;
  while (hi - lo > 1) {
    int mid = (lo + hi) >> 1;
    if (rowptr[mid] <= start) lo = mid; else hi = mid;
  }
  taskrow[task] = lo;
}

// ---- init: X=0, R=D0=B, SV=0 ----------------------------------------------
__global__ __launch_bounds__(256) void k_init_state(
    const int* __restrict__ labels, int Ns, float* __restrict__ X,
    float* __restrict__ R, float* __restrict__ D0, float* __restrict__ SV) {
  int idx = blockIdx.x * 256 + threadIdx.x;     // NN*64 total
  int i = idx >> 6, c = idx & 63;
  float b = (i < Ns && labels[i] == c) ? 1.0f : 0.0f;
  X[idx] = 0.0f; R[idx] = b; D0[idx] = b; SV[idx] = 0.0f;
}

// ------- pass 1: SV += (alpha*S) @ D, f32 gather, 1 task/wave ---------------
__global__ __launch_bounds__(256) void k_spmm(
    const int* __restrict__ rowptr, const int2* __restrict__ cv,
    const int* __restrict__ taskrow, const float* __restrict__ Dc,
    float* __restrict__ SV) {
  int lane = threadIdx.x & 63;
  int wave0 = (blockIdx.x * 256 + threadIdx.x) >> 6;
  int nwaves = (gridDim.x * 256) >> 6;
  int nnz = rowptr[NN];
  int ntask = (nnz + TASK - 1) / TASK;
  for (int task = wave0; task < ntask; task += nwaves) {
    int start = task * TASK;
    int end = start + TASK; if (end > nnz) end = nnz;
    float prod[TASK];
#pragma unroll
    for (int u = 0; u < TASK; ++u) {
      int p = start + u;
      if (p < end) {
        int2 c = cv[p];
        prod[u] = __int_as_float(c.y) * Dc[(size_t)c.x * 64 + lane];
      } else prod[u] = 0.0f;
    }
    int r = taskrow[task];
    int rend = rowptr[r + 1];
    float acc = 0.0f;
#pragma unroll
    for (int u = 0; u < TASK; ++u) {
      int p = start + u;
      if (p >= end) break;
      while (p >= rend) {
        atomicAdd(&SV[(size_t)r * 64 + lane], acc);
        acc = 0.0f; ++r; rend = rowptr[r + 1];
      }
      acc += prod[u];
    }
    atomicAdd(&SV[(size_t)r * 64 + lane], acc);
  }
}

// ------- pass 2: Chebyshev update (float4 streaming), re-zeros SV -----------
__global__ __launch_bounds__(256) void k_update(
    float* __restrict__ X, float* __restrict__ R, const float* __restrict__ Dcur,
    float* __restrict__ Dnxt, float* __restrict__ SV,
    const float* __restrict__ alphap, int it) {
  int idx = (blockIdx.x * 256 + threadIdx.x) * 4;   // grid = NN*64/1024
  float alpha = alphap[0];
  float sigma1 = 1.0f / alpha;
  float rho_prev = alpha;
  for (int k = 0; k < it; ++k) rho_prev = 1.0f / (2.0f * sigma1 - rho_prev);
  float rho = 1.0f / (2.0f * sigma1 - rho_prev);
  float c1 = rho * rho_prev, c2 = 2.0f * rho / alpha;
  float4 s = *(float4*)&SV[idx];
  *(float4*)&SV[idx] = make_float4(0.f, 0.f, 0.f, 0.f);
  float4 d = *(const float4*)&Dcur[idx];
  float4 x = *(float4*)&X[idx];
  float4 r = *(float4*)&R[idx];
  x.x += d.x; x.y += d.y; x.z += d.z; x.w += d.w;
  r.x -= (d.x - s.x); r.y -= (d.y - s.y); r.z -= (d.z - s.z); r.w -= (d.w - s.w);
  float4 dn;
  dn.x = c1 * d.x + c2 * r.x; dn.y = c1 * d.y + c2 * r.y;
  dn.z = c1 * d.z + c2 * r.z; dn.w = c1 * d.w + c2 * r.w;
  *(float4*)&X[idx] = x;
  *(float4*)&R[idx] = r;
  *(float4*)&Dnxt[idx] = dn;
}

// ---------------- host launch ----------------
static inline char* carve(char*& p, size_t bytes) {
  char* r = p;
  size_t a = (bytes + 255) & ~(size_t)255;
  p += a;
  return r;
}

extern "C" void kernel_launch(void* const* d_in, const int* in_sizes, int n_in,
                              void* d_out, int out_size, void* d_ws, size_t ws_size,
                              hipStream_t stream) {
  const float* emb    = (const float*)d_in[0];
  const float* sigma  = (const float*)d_in[1];
  const float* alphap = (const float*)d_in[2];
  const int*   labels = (const int*)d_in[3];
  const int*   kptr   = (const int*)d_in[4];
  int Ns = in_sizes[3];
  float* X = (float*)d_out;   // X state IS the output [NN][64]

  char* p = (char*)d_ws;
  _Float16* ehi    = (_Float16*)carve(p, (size_t)NN * DD * 2);
  _Float16* elo    = (_Float16*)carve(p, (size_t)NN * DD * 2);
  float*    sq     = (float*)carve(p, NN * 4);
  float*    Wm     = (float*)carve(p, (size_t)NN * NN * 4);
  int*      topk   = (int*)carve(p, NN * KMAX * 4);
  unsigned* mask   = (unsigned*)carve(p, NN * 128 * 4);
  float*    Dinv   = (float*)carve(p, NN * 4);
  int*      deg    = (int*)carve(p, NN * 4);
  int*      rowptr = (int*)carve(p, (NN + 1) * 4);
  int2*     cv     = (int2*)carve(p, (size_t)NNZ_CAP * 8);
  int*      trow   = (int*)carve(p, (size_t)MAXTASK * 4);
  float*    Rbuf   = (float*)carve(p, (size_t)NN * NCLS * 4);
  float*    SV     = (float*)carve(p, (size_t)NN * NCLS * 4);
  float*    Db0    = (float*)carve(p, (size_t)NN * NCLS * 4);
  float*    Db1    = (float*)carve(p, (size_t)NN * NCLS * 4);

  k_prep<<<NN, DD, 0, stream>>>(emb, sigma, ehi, elo, sq);
  k_gemmw<<<dim3(NN / 128, NN / 128), 256, 0, stream>>>(ehi, elo, sq, Wm);
  k_zero<<<(NN * 128 + 255) / 256, 256, 0, stream>>>(mask, NN * 128);
  k_topk<<<NN, 256, 0, stream>>>(Wm, topk, kptr);
  k_scatter<<<(NN * KMAX + 255) / 256, 256, 0, stream>>>(topk, mask, kptr);
  k_degree<<<NN, 128, 0, stream>>>(mask, Wm, Dinv, deg);
  k_scan<<<1, 256, 0, stream>>>(deg, rowptr);
  k_fill<<<NN, 128, 0, stream>>>(mask, Wm, Dinv, rowptr, cv, alphap);
  k_taskrow<<<(MAXTASK + 255) / 256, 256, 0, stream>>>(rowptr, trow);

  k_init_state<<<(NN * NCLS) / 256, 256, 0, stream>>>(labels, Ns, X, Rbuf, Db0, SV);
  for (int it = 0; it < NITER; ++it) {
    float* Dc = (it & 1) ? Db1 : Db0;
    float* Dn = (it & 1) ? Db0 : Db1;
    k_spmm<<<1280, 256, 0, stream>>>(rowptr, cv, trow, Dc, SV);
    k_update<<<(NN * NCLS) / 1024, 256, 0, stream>>>(X, Rbuf, Dc, Dn, SV, alphap, it);
  }
}

// Round 15
// 1186.813 us; speedup vs baseline: 7.7897x; 1.0782x over previous
//
#include <hip/hip_runtime.h>
#include <math.h>

#define NN 4096
#define DD 256
#define NCLS 64
#define EPSF 2.2204460492503131e-16f
#define NITER 40
#define KMAX 64
#define TASK 32                      // nnz per wave-task
#define NNZ_CAP (NN * 2 * KMAX)
#define MAXTASK (NNZ_CAP / TASK)
#define LDP 40                       // padded LDS row (halves): 80B stride

typedef __attribute__((ext_vector_type(8))) _Float16 half8;
typedef __attribute__((ext_vector_type(4))) float f32x4;

// ---- prep: e = emb/(sigma+eps)^2, split into f16 hi/lo, sq = rowsum(e*e) ----
__global__ void k_prep(const float* __restrict__ emb, const float* __restrict__ sig,
                       _Float16* __restrict__ ehi, _Float16* __restrict__ elo,
                       float* __restrict__ sq) {
  int row = blockIdx.x, t = threadIdx.x;  // block = 256 = DD
  float s = sig[row] + EPSF;
  float v = emb[row * DD + t];
  v = v / s; v = v / s;
  _Float16 h = (_Float16)v;
  _Float16 l = (_Float16)(v - (float)h);
  ehi[row * DD + t] = h;
  elo[row * DD + t] = l;
  __shared__ float red[DD];
  red[t] = v * v; __syncthreads();
  for (int off = 128; off > 0; off >>= 1) {
    if (t < off) red[t] += red[t + off];
    __syncthreads();
  }
  if (t == 0) sq[row] = red[0];
}

// ---- dense W = exp(-dist/2) via f16 split MFMA: G = e e^T (C = A.B^T) ------
__global__ __launch_bounds__(256) void k_gemmw(
    const _Float16* __restrict__ ehi, const _Float16* __restrict__ elo,
    const float* __restrict__ sq, float* __restrict__ W) {
  __shared__ _Float16 Ah[128][LDP];
  __shared__ _Float16 Al[128][LDP];
  __shared__ _Float16 Bh[128][LDP];
  __shared__ _Float16 Bl[128][LDP];
  int t = threadIdx.x;
  int lane = t & 63, wv = t >> 6;
  int wm = wv >> 1, wn = wv & 1;
  int rowbase = blockIdx.y * 128, colbase = blockIdx.x * 128;
  f32x4 acc[4][4];
#pragma unroll
  for (int m = 0; m < 4; ++m)
#pragma unroll
    for (int n = 0; n < 4; ++n) acc[m][n] = (f32x4){0.f, 0.f, 0.f, 0.f};
  int fr = lane & 15, kc = (lane >> 4) * 8;
  for (int k0 = 0; k0 < DD; k0 += 32) {
    for (int q = t; q < 512; q += 256) {
      int lr = q >> 2, ls = (q & 3) * 8;
      size_t ga = (size_t)(rowbase + lr) * DD + k0 + ls;
      size_t gb = (size_t)(colbase + lr) * DD + k0 + ls;
      *(uint4*)&Ah[lr][ls] = *(const uint4*)&ehi[ga];
      *(uint4*)&Al[lr][ls] = *(const uint4*)&elo[ga];
      *(uint4*)&Bh[lr][ls] = *(const uint4*)&ehi[gb];
      *(uint4*)&Bl[lr][ls] = *(const uint4*)&elo[gb];
    }
    __syncthreads();
    half8 ah[4], al[4], bh[4], bl[4];
#pragma unroll
    for (int m = 0; m < 4; ++m) {
      ah[m] = *(const half8*)&Ah[wm * 64 + m * 16 + fr][kc];
      al[m] = *(const half8*)&Al[wm * 64 + m * 16 + fr][kc];
    }
#pragma unroll
    for (int n = 0; n < 4; ++n) {
      bh[n] = *(const half8*)&Bh[wn * 64 + n * 16 + fr][kc];
      bl[n] = *(const half8*)&Bl[wn * 64 + n * 16 + fr][kc];
    }
#pragma unroll
    for (int m = 0; m < 4; ++m)
#pragma unroll
      for (int n = 0; n < 4; ++n) {
        acc[m][n] = __builtin_amdgcn_mfma_f32_16x16x32_f16(ah[m], bh[n], acc[m][n], 0, 0, 0);
        acc[m][n] = __builtin_amdgcn_mfma_f32_16x16x32_f16(ah[m], bl[n], acc[m][n], 0, 0, 0);
        acc[m][n] = __builtin_amdgcn_mfma_f32_16x16x32_f16(al[m], bh[n], acc[m][n], 0, 0, 0);
      }
    __syncthreads();
  }
#pragma unroll
  for (int m = 0; m < 4; ++m) {
#pragma unroll
    for (int reg = 0; reg < 4; ++reg) {
      int i = rowbase + wm * 64 + m * 16 + (lane >> 4) * 4 + reg;
      float sqi = sq[i];
#pragma unroll
      for (int n = 0; n < 4; ++n) {
        int j = colbase + wn * 64 + n * 16 + (lane & 15);
        float dist = (sqi + sq[j] - 2.0f * acc[m][n][reg]) * (1.0f / DD);
        W[(size_t)i * NN + j] = expf(-0.5f * dist);
      }
    }
  }
}

// ---------------- zero a u32 buffer ----------------
__global__ void k_zero(unsigned* __restrict__ p, int n) {
  int i = blockIdx.x * blockDim.x + threadIdx.x;
  if (i < n) p[i] = 0u;
}

// ---- per-row top-k (R8 proven): 4 waves x 1024 elems, 16/lane --------------
// ties: higher value wins; equal value -> lower column (matches jax top_k).
__global__ __launch_bounds__(256) void k_topk(const float* __restrict__ W,
                                              int* __restrict__ idx,
                                              const int* __restrict__ kptr) {
  int row = blockIdx.x;
  int t = threadIdx.x, lane = t & 63, w = t >> 6;
  int K = kptr[0]; if (K > KMAX) K = KMAX;
  const float* Wr = &W[(size_t)row * NN];
  float val[16];
#pragma unroll
  for (int i = 0; i < 16; ++i) val[i] = Wr[w * 1024 + i * 64 + lane];
  unsigned rm = 0;
  __shared__ float lv[4][KMAX];
  __shared__ int   lc[4][KMAX];
  for (int k = 0; k < K; ++k) {
    float vb = -1e38f; int cb = 0x7fffffff;
#pragma unroll
    for (int i = 0; i < 16; ++i) {
      bool ok = !((rm >> i) & 1u);
      if (ok && val[i] > vb) { vb = val[i]; cb = w * 1024 + i * 64 + lane; }
    }
    for (int off = 32; off > 0; off >>= 1) {
      float ov = __shfl_xor(vb, off, 64);
      int   oc = __shfl_xor(cb, off, 64);
      if (ov > vb || (ov == vb && oc < cb)) { vb = ov; cb = oc; }
    }
    if ((cb & 63) == lane) { int i = (cb >> 6) & 15; rm |= 1u << i; }
    if (lane == 0) { lv[w][k] = vb; lc[w][k] = cb; }
  }
  __syncthreads();
  if (w == 0) {
    float cv[4]; int cc[4]; unsigned crm = 0;
#pragma unroll
    for (int j = 0; j < 4; ++j) {
      if (lane < K) { cv[j] = lv[j][lane]; cc[j] = lc[j][lane]; }
      else { cv[j] = -1e38f; cc[j] = 0x7fffffff; }
    }
    for (int k = 0; k < K; ++k) {
      float vb = -1e38f; int cb = 0x7fffffff;
#pragma unroll
      for (int j = 0; j < 4; ++j) {
        bool ok = !((crm >> j) & 1u);
        if (ok && (cv[j] > vb || (cv[j] == vb && cc[j] < cb))) { vb = cv[j]; cb = cc[j]; }
      }
      for (int off = 32; off > 0; off >>= 1) {
        float ov = __shfl_xor(vb, off, 64);
        int   oc = __shfl_xor(cb, off, 64);
        if (ov > vb || (ov == vb && oc < cb)) { vb = ov; cb = oc; }
      }
#pragma unroll
      for (int j = 0; j < 4; ++j) if (cc[j] == cb) crm |= 1u << j;
      if (lane == 0) idx[row * KMAX + k] = cb;
    }
  }
}

// ---------------- scatter symmetric bitmask ----------------
__global__ void k_scatter(const int* __restrict__ idx, unsigned* __restrict__ mask,
                          const int* __restrict__ kptr) {
  int K = kptr[0]; if (K > KMAX) K = KMAX;
  int tid = blockIdx.x * blockDim.x + threadIdx.x;
  if (tid >= NN * K) return;
  int i = tid / K, k = tid % K;
  int j = idx[i * KMAX + k];
  atomicOr(&mask[i * 128 + (j >> 5)], 1u << (j & 31));
  atomicOr(&mask[j * 128 + (i >> 5)], 1u << (i & 31));
}

// ---------------- degree (sum of masked W per row) + Dinv ------------
__global__ void k_degree(const unsigned* __restrict__ mask, const float* __restrict__ W,
                         float* __restrict__ Dinv, int* __restrict__ deg) {
  int row = blockIdx.x, t = threadIdx.x;  // block = 128
  unsigned m = mask[row * 128 + t];
  float dsum = 0.f; int cnt = __popc(m);
  unsigned mm = m;
  while (mm) {
    int b = __ffs(mm) - 1; mm &= mm - 1;
    dsum += W[(size_t)row * NN + t * 32 + b];
  }
  __shared__ float rs[128];
  __shared__ int   rc[128];
  rs[t] = dsum; rc[t] = cnt; __syncthreads();
  for (int off = 64; off > 0; off >>= 1) {
    if (t < off) { rs[t] += rs[t + off]; rc[t] += rc[t + off]; }
    __syncthreads();
  }
  if (t == 0) { deg[row] = rc[0]; Dinv[row] = sqrtf(1.0f / (rs[0] + EPSF)); }
}

// ------- exclusive scan of deg -> rowptr (one block, shuffle scan) ----------
__global__ void k_scan(const int* __restrict__ deg, int* __restrict__ rowptr) {
  int t = threadIdx.x;
  int lane = t & 63, w = t >> 6;
  int loc[16]; int s = 0;
  for (int u = 0; u < 16; ++u) { loc[u] = s; s += deg[t * 16 + u]; }
  int tot = s, inc = s;
  for (int off = 1; off < 64; off <<= 1) {
    int n = __shfl_up(inc, off, 64);
    if (lane >= off) inc += n;
  }
  __shared__ int wt[4];
  if (lane == 63) wt[w] = inc;
  __syncthreads();
  int base = 0;
  for (int u = 0; u < w; ++u) base += wt[u];
  int excl = base + inc - tot;
  for (int u = 0; u < 16; ++u) rowptr[t * 16 + u] = excl + loc[u];
  if (t == 255) rowptr[NN] = excl + tot;
}

// ---------------- fill CSR of alpha*S, packed (col, val) --------------------
__global__ void k_fill(const unsigned* __restrict__ mask, const float* __restrict__ W,
                       const float* __restrict__ Dinv, const int* __restrict__ rowptr,
                       int2* __restrict__ cv, const float* __restrict__ alphap) {
  int row = blockIdx.x, t = threadIdx.x;  // block = 128
  float alpha = alphap[0];
  unsigned m = mask[row * 128 + t];
  __shared__ int wcnt[128];
  wcnt[t] = __popc(m); __syncthreads();
  int pre = 0;
  for (int u = 0; u < t; ++u) pre += wcnt[u];
  int base = rowptr[row] + pre;
  float di = Dinv[row];
  while (m) {
    int b = __ffs(m) - 1; m &= m - 1;
    int j = t * 32 + b;
    float v = alpha * W[(size_t)row * NN + j] * di * Dinv[j];
    cv[base] = make_int2(j, __float_as_int(v));
    ++base;
  }
}

// ------- precompute task -> starting row ------
__global__ void k_taskrow(const int* __restrict__ rowptr, int* __restrict__ taskrow) {
  int task = blockIdx.x * blockDim.x + threadIdx.x;
  int nnz = rowptr[NN];
  int ntask = (nnz + TASK - 1) / TASK;
  if (task >= ntask) return;
  int start = task * TASK;
  int lo = 0, hi = NN;
  while (hi - lo > 1) {
    int mid = (lo + hi) >> 1;
    if (rowptr[mid] <= start) lo = mid; else hi = mid;
  }
  taskrow[task] = lo;
}

// ---- init: X=0, R=D0=B, SV=0 ----------------------------------------------
__global__ __launch_bounds__(256) void k_init_state(
    const int* __restrict__ labels, int Ns, float* __restrict__ X,
    float* __restrict__ R, float* __restrict__ D0, float* __restrict__ SV) {
  int idx = blockIdx.x * 256 + threadIdx.x;     // NN*64 total
  int i = idx >> 6, c = idx & 63;
  float b = (i < Ns && labels[i] == c) ? 1.0f : 0.0f;
  X[idx] = 0.0f; R[idx] = b; D0[idx] = b; SV[idx] = 0.0f;
}

// ------- pass 1: SV += (alpha*S) @ D, f32 gather, 1 task/wave ---------------
__global__ __launch_bounds__(256) void k_spmm(
    const int* __restrict__ rowptr, const int2* __restrict__ cv,
    const int* __restrict__ taskrow, const float* __restrict__ Dc,
    float* __restrict__ SV) {
  int lane = threadIdx.x & 63;
  int wave0 = (blockIdx.x * 256 + threadIdx.x) >> 6;
  int nwaves = (gridDim.x * 256) >> 6;
  int nnz = rowptr[NN];
  int ntask = (nnz + TASK - 1) / TASK;
  for (int task = wave0; task < ntask; task += nwaves) {
    int start = task * TASK;
    int end = start + TASK; if (end > nnz) end = nnz;
    float prod[TASK];
#pragma unroll
    for (int u = 0; u < TASK; ++u) {
      int p = start + u;
      if (p < end) {
        int2 c = cv[p];
        prod[u] = __int_as_float(c.y) * Dc[(size_t)c.x * 64 + lane];
      } else prod[u] = 0.0f;
    }
    int r = taskrow[task];
    int rend = rowptr[r + 1];
    float acc = 0.0f;
#pragma unroll
    for (int u = 0; u < TASK; ++u) {
      int p = start + u;
      if (p >= end) break;
      while (p >= rend) {
        atomicAdd(&SV[(size_t)r * 64 + lane], acc);
        acc = 0.0f; ++r; rend = rowptr[r + 1];
      }
      acc += prod[u];
    }
    atomicAdd(&SV[(size_t)r * 64 + lane], acc);
  }
}

// ------- pass 2: Chebyshev update (float2 streaming, 8 waves/CU) ------------
__global__ __launch_bounds__(256) void k_update(
    float* __restrict__ X, float* __restrict__ R, const float* __restrict__ Dcur,
    float* __restrict__ Dnxt, float* __restrict__ SV,
    const float* __restrict__ alphap, int it) {
  int idx = (blockIdx.x * 256 + threadIdx.x) * 2;   // grid = NN*64/512 blocks
  float alpha = alphap[0];
  float sigma1 = 1.0f / alpha;
  float rho_prev = alpha;
  for (int k = 0; k < it; ++k) rho_prev = 1.0f / (2.0f * sigma1 - rho_prev);
  float rho = 1.0f / (2.0f * sigma1 - rho_prev);
  float c1 = rho * rho_prev, c2 = 2.0f * rho / alpha;
  float2 s = *(float2*)&SV[idx];
  *(float2*)&SV[idx] = make_float2(0.f, 0.f);
  float2 d = *(const float2*)&Dcur[idx];
  float2 x = *(float2*)&X[idx];
  float2 r = *(float2*)&R[idx];
  x.x += d.x; x.y += d.y;
  r.x -= (d.x - s.x); r.y -= (d.y - s.y);
  float2 dn;
  dn.x = c1 * d.x + c2 * r.x; dn.y = c1 * d.y + c2 * r.y;
  *(float2*)&X[idx] = x;
  *(float2*)&R[idx] = r;
  *(float2*)&Dnxt[idx] = dn;
}

// ---------------- host launch ----------------
static inline char* carve(char*& p, size_t bytes) {
  char* r = p;
  size_t a = (bytes + 255) & ~(size_t)255;
  p += a;
  return r;
}

extern "C" void kernel_launch(void* const* d_in, const int* in_sizes, int n_in,
                              void* d_out, int out_size, void* d_ws, size_t ws_size,
                              hipStream_t stream) {
  const float* emb    = (const float*)d_in[0];
  const float* sigma  = (const float*)d_in[1];
  const float* alphap = (const float*)d_in[2];
  const int*   labels = (const int*)d_in[3];
  const int*   kptr   = (const int*)d_in[4];
  int Ns = in_sizes[3];
  float* X = (float*)d_out;   // X state IS the output [NN][64]

  char* p = (char*)d_ws;
  _Float16* ehi    = (_Float16*)carve(p, (size_t)NN * DD * 2);
  _Float16* elo    = (_Float16*)carve(p, (size_t)NN * DD * 2);
  float*    sq     = (float*)carve(p, NN * 4);
  float*    Wm     = (float*)carve(p, (size_t)NN * NN * 4);
  int*      topk   = (int*)carve(p, NN * KMAX * 4);
  unsigned* mask   = (unsigned*)carve(p, NN * 128 * 4);
  float*    Dinv   = (float*)carve(p, NN * 4);
  int*      deg    = (int*)carve(p, NN * 4);
  int*      rowptr = (int*)carve(p, (NN + 1) * 4);
  int2*     cv     = (int2*)carve(p, (size_t)NNZ_CAP * 8);
  int*      trow   = (int*)carve(p, (size_t)MAXTASK * 4);
  float*    Rbuf   = (float*)carve(p, (size_t)NN * NCLS * 4);
  float*    SV     = (float*)carve(p, (size_t)NN * NCLS * 4);
  float*    Db0    = (float*)carve(p, (size_t)NN * NCLS * 4);
  float*    Db1    = (float*)carve(p, (size_t)NN * NCLS * 4);

  k_prep<<<NN, DD, 0, stream>>>(emb, sigma, ehi, elo, sq);
  k_gemmw<<<dim3(NN / 128, NN / 128), 256, 0, stream>>>(ehi, elo, sq, Wm);
  k_zero<<<(NN * 128 + 255) / 256, 256, 0, stream>>>(mask, NN * 128);
  k_topk<<<NN, 256, 0, stream>>>(Wm, topk, kptr);
  k_scatter<<<(NN * KMAX + 255) / 256, 256, 0, stream>>>(topk, mask, kptr);
  k_degree<<<NN, 128, 0, stream>>>(mask, Wm, Dinv, deg);
  k_scan<<<1, 256, 0, stream>>>(deg, rowptr);
  k_fill<<<NN, 128, 0, stream>>>(mask, Wm, Dinv, rowptr, cv, alphap);
  k_taskrow<<<(MAXTASK + 255) / 256, 256, 0, stream>>>(rowptr, trow);

  k_init_state<<<(NN * NCLS) / 256, 256, 0, stream>>>(labels, Ns, X, Rbuf, Db0, SV);
  for (int it = 0; it < NITER; ++it) {
    float* Dc = (it & 1) ? Db1 : Db0;
    float* Dn = (it & 1) ? Db0 : Db1;
    k_spmm<<<1280, 256, 0, stream>>>(rowptr, cv, trow, Dc, SV);
    k_update<<<(NN * NCLS) / 512, 256, 0, stream>>>(X, Rbuf, Dc, Dn, SV, alphap, it);
  }
}

// Round 16
// 1158.905 us; speedup vs baseline: 7.9773x; 1.0241x over previous
//
#include <hip/hip_runtime.h>
#include <math.h>

#define NN 4096
#define DD 256
#define NCLS 64
#define EPSF 2.2204460492503131e-16f
#define NITER 40
#define KMAX 64
#define TASK 32                      // nnz per wave-task
#define NNZ_CAP (NN * 2 * KMAX)
#define MAXTASK (NNZ_CAP / TASK)
#define LDP 40                       // padded LDS row (halves): 80B stride

typedef __attribute__((ext_vector_type(8))) _Float16 half8;
typedef __attribute__((ext_vector_type(4))) float f32x4;

// ---- prep: e = emb/(sigma+eps)^2, split into f16 hi/lo, sq = rowsum(e*e) ----
__global__ void k_prep(const float* __restrict__ emb, const float* __restrict__ sig,
                       _Float16* __restrict__ ehi, _Float16* __restrict__ elo,
                       float* __restrict__ sq) {
  int row = blockIdx.x, t = threadIdx.x;  // block = 256 = DD
  float s = sig[row] + EPSF;
  float v = emb[row * DD + t];
  v = v / s; v = v / s;
  _Float16 h = (_Float16)v;
  _Float16 l = (_Float16)(v - (float)h);
  ehi[row * DD + t] = h;
  elo[row * DD + t] = l;
  __shared__ float red[DD];
  red[t] = v * v; __syncthreads();
  for (int off = 128; off > 0; off >>= 1) {
    if (t < off) red[t] += red[t + off];
    __syncthreads();
  }
  if (t == 0) sq[row] = red[0];
}

// ---- dense W = exp(-dist/2) via f16 split MFMA: G = e e^T (C = A.B^T) ------
__global__ __launch_bounds__(256) void k_gemmw(
    const _Float16* __restrict__ ehi, const _Float16* __restrict__ elo,
    const float* __restrict__ sq, float* __restrict__ W) {
  __shared__ _Float16 Ah[128][LDP];
  __shared__ _Float16 Al[128][LDP];
  __shared__ _Float16 Bh[128][LDP];
  __shared__ _Float16 Bl[128][LDP];
  int t = threadIdx.x;
  int lane = t & 63, wv = t >> 6;
  int wm = wv >> 1, wn = wv & 1;
  int rowbase = blockIdx.y * 128, colbase = blockIdx.x * 128;
  f32x4 acc[4][4];
#pragma unroll
  for (int m = 0; m < 4; ++m)
#pragma unroll
    for (int n = 0; n < 4; ++n) acc[m][n] = (f32x4){0.f, 0.f, 0.f, 0.f};
  int fr = lane & 15, kc = (lane >> 4) * 8;
  for (int k0 = 0; k0 < DD; k0 += 32) {
    for (int q = t; q < 512; q += 256) {
      int lr = q >> 2, ls = (q & 3) * 8;
      size_t ga = (size_t)(rowbase + lr) * DD + k0 + ls;
      size_t gb = (size_t)(colbase + lr) * DD + k0 + ls;
      *(uint4*)&Ah[lr][ls] = *(const uint4*)&ehi[ga];
      *(uint4*)&Al[lr][ls] = *(const uint4*)&elo[ga];
      *(uint4*)&Bh[lr][ls] = *(const uint4*)&ehi[gb];
      *(uint4*)&Bl[lr][ls] = *(const uint4*)&elo[gb];
    }
    __syncthreads();
    half8 ah[4], al[4], bh[4], bl[4];
#pragma unroll
    for (int m = 0; m < 4; ++m) {
      ah[m] = *(const half8*)&Ah[wm * 64 + m * 16 + fr][kc];
      al[m] = *(const half8*)&Al[wm * 64 + m * 16 + fr][kc];
    }
#pragma unroll
    for (int n = 0; n < 4; ++n) {
      bh[n] = *(const half8*)&Bh[wn * 64 + n * 16 + fr][kc];
      bl[n] = *(const half8*)&Bl[wn * 64 + n * 16 + fr][kc];
    }
#pragma unroll
    for (int m = 0; m < 4; ++m)
#pragma unroll
      for (int n = 0; n < 4; ++n) {
        acc[m][n] = __builtin_amdgcn_mfma_f32_16x16x32_f16(ah[m], bh[n], acc[m][n], 0, 0, 0);
        acc[m][n] = __builtin_amdgcn_mfma_f32_16x16x32_f16(ah[m], bl[n], acc[m][n], 0, 0, 0);
        acc[m][n] = __builtin_amdgcn_mfma_f32_16x16x32_f16(al[m], bh[n], acc[m][n], 0, 0, 0);
      }
    __syncthreads();
  }
#pragma unroll
  for (int m = 0; m < 4; ++m) {
#pragma unroll
    for (int reg = 0; reg < 4; ++reg) {
      int i = rowbase + wm * 64 + m * 16 + (lane >> 4) * 4 + reg;
      float sqi = sq[i];
#pragma unroll
      for (int n = 0; n < 4; ++n) {
        int j = colbase + wn * 64 + n * 16 + (lane & 15);
        float dist = (sqi + sq[j] - 2.0f * acc[m][n][reg]) * (1.0f / DD);
        W[(size_t)i * NN + j] = expf(-0.5f * dist);
      }
    }
  }
}

// ---------------- zero a u32 buffer ----------------
__global__ void k_zero(unsigned* __restrict__ p, int n) {
  int i = blockIdx.x * blockDim.x + threadIdx.x;
  if (i < n) p[i] = 0u;
}

// ---- per-row top-k (R8 proven): 4 waves x 1024 elems, 16/lane --------------
// ties: higher value wins; equal value -> lower column (matches jax top_k).
__global__ __launch_bounds__(256) void k_topk(const float* __restrict__ W,
                                              int* __restrict__ idx,
                                              const int* __restrict__ kptr) {
  int row = blockIdx.x;
  int t = threadIdx.x, lane = t & 63, w = t >> 6;
  int K = kptr[0]; if (K > KMAX) K = KMAX;
  const float* Wr = &W[(size_t)row * NN];
  float val[16];
#pragma unroll
  for (int i = 0; i < 16; ++i) val[i] = Wr[w * 1024 + i * 64 + lane];
  unsigned rm = 0;
  __shared__ float lv[4][KMAX];
  __shared__ int   lc[4][KMAX];
  for (int k = 0; k < K; ++k) {
    float vb = -1e38f; int cb = 0x7fffffff;
#pragma unroll
    for (int i = 0; i < 16; ++i) {
      bool ok = !((rm >> i) & 1u);
      if (ok && val[i] > vb) { vb = val[i]; cb = w * 1024 + i * 64 + lane; }
    }
    for (int off = 32; off > 0; off >>= 1) {
      float ov = __shfl_xor(vb, off, 64);
      int   oc = __shfl_xor(cb, off, 64);
      if (ov > vb || (ov == vb && oc < cb)) { vb = ov; cb = oc; }
    }
    if ((cb & 63) == lane) { int i = (cb >> 6) & 15; rm |= 1u << i; }
    if (lane == 0) { lv[w][k] = vb; lc[w][k] = cb; }
  }
  __syncthreads();
  if (w == 0) {
    float cv[4]; int cc[4]; unsigned crm = 0;
#pragma unroll
    for (int j = 0; j < 4; ++j) {
      if (lane < K) { cv[j] = lv[j][lane]; cc[j] = lc[j][lane]; }
      else { cv[j] = -1e38f; cc[j] = 0x7fffffff; }
    }
    for (int k = 0; k < K; ++k) {
      float vb = -1e38f; int cb = 0x7fffffff;
#pragma unroll
      for (int j = 0; j < 4; ++j) {
        bool ok = !((crm >> j) & 1u);
        if (ok && (cv[j] > vb || (cv[j] == vb && cc[j] < cb))) { vb = cv[j]; cb = cc[j]; }
      }
      for (int off = 32; off > 0; off >>= 1) {
        float ov = __shfl_xor(vb, off, 64);
        int   oc = __shfl_xor(cb, off, 64);
        if (ov > vb || (ov == vb && oc < cb)) { vb = ov; cb = oc; }
      }
#pragma unroll
      for (int j = 0; j < 4; ++j) if (cc[j] == cb) crm |= 1u << j;
      if (lane == 0) idx[row * KMAX + k] = cb;
    }
  }
}

// ---------------- scatter symmetric bitmask ----------------
__global__ void k_scatter(const int* __restrict__ idx, unsigned* __restrict__ mask,
                          const int* __restrict__ kptr) {
  int K = kptr[0]; if (K > KMAX) K = KMAX;
  int tid = blockIdx.x * blockDim.x + threadIdx.x;
  if (tid >= NN * K) return;
  int i = tid / K, k = tid % K;
  int j = idx[i * KMAX + k];
  atomicOr(&mask[i * 128 + (j >> 5)], 1u << (j & 31));
  atomicOr(&mask[j * 128 + (i >> 5)], 1u << (i & 31));
}

// ---------------- degree (sum of masked W per row) + Dinv ------------
__global__ void k_degree(const unsigned* __restrict__ mask, const float* __restrict__ W,
                         float* __restrict__ Dinv, int* __restrict__ deg) {
  int row = blockIdx.x, t = threadIdx.x;  // block = 128
  unsigned m = mask[row * 128 + t];
  float dsum = 0.f; int cnt = __popc(m);
  unsigned mm = m;
  while (mm) {
    int b = __ffs(mm) - 1; mm &= mm - 1;
    dsum += W[(size_t)row * NN + t * 32 + b];
  }
  __shared__ float rs[128];
  __shared__ int   rc[128];
  rs[t] = dsum; rc[t] = cnt; __syncthreads();
  for (int off = 64; off > 0; off >>= 1) {
    if (t < off) { rs[t] += rs[t + off]; rc[t] += rc[t + off]; }
    __syncthreads();
  }
  if (t == 0) { deg[row] = rc[0]; Dinv[row] = sqrtf(1.0f / (rs[0] + EPSF)); }
}

// ------- exclusive scan of deg -> rowptr (one block, shuffle scan) ----------
__global__ void k_scan(const int* __restrict__ deg, int* __restrict__ rowptr) {
  int t = threadIdx.x;
  int lane = t & 63, w = t >> 6;
  int loc[16]; int s = 0;
  for (int u = 0; u < 16; ++u) { loc[u] = s; s += deg[t * 16 + u]; }
  int tot = s, inc = s;
  for (int off = 1; off < 64; off <<= 1) {
    int n = __shfl_up(inc, off, 64);
    if (lane >= off) inc += n;
  }
  __shared__ int wt[4];
  if (lane == 63) wt[w] = inc;
  __syncthreads();
  int base = 0;
  for (int u = 0; u < w; ++u) base += wt[u];
  int excl = base + inc - tot;
  for (int u = 0; u < 16; ++u) rowptr[t * 16 + u] = excl + loc[u];
  if (t == 255) rowptr[NN] = excl + tot;
}

// ---------------- fill CSR of alpha*S, packed (col, val) --------------------
__global__ void k_fill(const unsigned* __restrict__ mask, const float* __restrict__ W,
                       const float* __restrict__ Dinv, const int* __restrict__ rowptr,
                       int2* __restrict__ cv, const float* __restrict__ alphap) {
  int row = blockIdx.x, t = threadIdx.x;  // block = 128
  float alpha = alphap[0];
  unsigned m = mask[row * 128 + t];
  __shared__ int wcnt[128];
  wcnt[t] = __popc(m); __syncthreads();
  int pre = 0;
  for (int u = 0; u < t; ++u) pre += wcnt[u];
  int base = rowptr[row] + pre;
  float di = Dinv[row];
  while (m) {
    int b = __ffs(m) - 1; m &= m - 1;
    int j = t * 32 + b;
    float v = alpha * W[(size_t)row * NN + j] * di * Dinv[j];
    cv[base] = make_int2(j, __float_as_int(v));
    ++base;
  }
}

// ------- precompute task -> starting row ------
__global__ void k_taskrow(const int* __restrict__ rowptr, int* __restrict__ taskrow) {
  int task = blockIdx.x * blockDim.x + threadIdx.x;
  int nnz = rowptr[NN];
  int ntask = (nnz + TASK - 1) / TASK;
  if (task >= ntask) return;
  int start = task * TASK;
  int lo = 0, hi = NN;
  while (hi - lo > 1) {
    int mid = (lo + hi) >> 1;
    if (rowptr[mid] <= start) lo = mid; else hi = mid;
  }
  taskrow[task] = lo;
}

// ---- init: X=0, R=D0=B (f32 + f16 mirror), SV=0 ----------------------------
__global__ __launch_bounds__(256) void k_init_state(
    const int* __restrict__ labels, int Ns, float* __restrict__ X,
    float* __restrict__ R, float* __restrict__ D0,
    _Float16* __restrict__ H0, float* __restrict__ SV) {
  int idx = blockIdx.x * 256 + threadIdx.x;     // NN*64 total
  int i = idx >> 6, c = idx & 63;
  float b = (i < Ns && labels[i] == c) ? 1.0f : 0.0f;
  X[idx] = 0.0f; R[idx] = b; D0[idx] = b; H0[idx] = (_Float16)b; SV[idx] = 0.0f;
}

// ------- pass 1: SV += (alpha*S) @ D, f16 gather (2 L2 lines/nnz) -----------
__global__ __launch_bounds__(256) void k_spmm(
    const int* __restrict__ rowptr, const int2* __restrict__ cv,
    const int* __restrict__ taskrow, const _Float16* __restrict__ H,
    float* __restrict__ SV) {
  int lane = threadIdx.x & 63;
  int wave0 = (blockIdx.x * 256 + threadIdx.x) >> 6;
  int nwaves = (gridDim.x * 256) >> 6;
  int nnz = rowptr[NN];
  int ntask = (nnz + TASK - 1) / TASK;
  for (int task = wave0; task < ntask; task += nwaves) {
    int start = task * TASK;
    int end = start + TASK; if (end > nnz) end = nnz;
    float prod[TASK];
#pragma unroll
    for (int u = 0; u < TASK; ++u) {
      int p = start + u;
      if (p < end) {
        int2 c = cv[p];
        prod[u] = __int_as_float(c.y) * (float)H[(size_t)c.x * 64 + lane];
      } else prod[u] = 0.0f;
    }
    int r = taskrow[task];
    int rend = rowptr[r + 1];
    float acc = 0.0f;
#pragma unroll
    for (int u = 0; u < TASK; ++u) {
      int p = start + u;
      if (p >= end) break;
      while (p >= rend) {
        atomicAdd(&SV[(size_t)r * 64 + lane], acc);
        acc = 0.0f; ++r; rend = rowptr[r + 1];
      }
      acc += prod[u];
    }
    atomicAdd(&SV[(size_t)r * 64 + lane], acc);
  }
}

// ------- pass 2: Chebyshev update (float2 streaming), writes f16 mirror -----
__global__ __launch_bounds__(256) void k_update(
    float* __restrict__ X, float* __restrict__ R, const float* __restrict__ Dcur,
    float* __restrict__ Dnxt, _Float16* __restrict__ Hnxt,
    float* __restrict__ SV, const float* __restrict__ alphap, int it) {
  int idx = (blockIdx.x * 256 + threadIdx.x) * 2;   // grid = NN*64/512 blocks
  float alpha = alphap[0];
  float sigma1 = 1.0f / alpha;
  float rho_prev = alpha;
  for (int k = 0; k < it; ++k) rho_prev = 1.0f / (2.0f * sigma1 - rho_prev);
  float rho = 1.0f / (2.0f * sigma1 - rho_prev);
  float c1 = rho * rho_prev, c2 = 2.0f * rho / alpha;
  float2 s = *(float2*)&SV[idx];
  *(float2*)&SV[idx] = make_float2(0.f, 0.f);
  float2 d = *(const float2*)&Dcur[idx];
  float2 x = *(float2*)&X[idx];
  float2 r = *(float2*)&R[idx];
  x.x += d.x; x.y += d.y;
  r.x -= (d.x - s.x); r.y -= (d.y - s.y);
  float2 dn;
  dn.x = c1 * d.x + c2 * r.x; dn.y = c1 * d.y + c2 * r.y;
  *(float2*)&X[idx] = x;
  *(float2*)&R[idx] = r;
  *(float2*)&Dnxt[idx] = dn;
  _Float16 h2[2] = {(_Float16)dn.x, (_Float16)dn.y};
  *(uint*)&Hnxt[idx] = *(uint*)h2;
}

// ---------------- host launch ----------------
static inline char* carve(char*& p, size_t bytes) {
  char* r = p;
  size_t a = (bytes + 255) & ~(size_t)255;
  p += a;
  return r;
}

extern "C" void kernel_launch(void* const* d_in, const int* in_sizes, int n_in,
                              void* d_out, int out_size, void* d_ws, size_t ws_size,
                              hipStream_t stream) {
  const float* emb    = (const float*)d_in[0];
  const float* sigma  = (const float*)d_in[1];
  const float* alphap = (const float*)d_in[2];
  const int*   labels = (const int*)d_in[3];
  const int*   kptr   = (const int*)d_in[4];
  int Ns = in_sizes[3];
  float* X = (float*)d_out;   // X state IS the output [NN][64]

  char* p = (char*)d_ws;
  _Float16* ehi    = (_Float16*)carve(p, (size_t)NN * DD * 2);
  _Float16* elo    = (_Float16*)carve(p, (size_t)NN * DD * 2);
  float*    sq     = (float*)carve(p, NN * 4);
  float*    Wm     = (float*)carve(p, (size_t)NN * NN * 4);
  int*      topk   = (int*)carve(p, NN * KMAX * 4);
  unsigned* mask   = (unsigned*)carve(p, NN * 128 * 4);
  float*    Dinv   = (float*)carve(p, NN * 4);
  int*      deg    = (int*)carve(p, NN * 4);
  int*      rowptr = (int*)carve(p, (NN + 1) * 4);
  int2*     cv     = (int2*)carve(p, (size_t)NNZ_CAP * 8);
  int*      trow   = (int*)carve(p, (size_t)MAXTASK * 4);
  float*    Rbuf   = (float*)carve(p, (size_t)NN * NCLS * 4);
  float*    SV     = (float*)carve(p, (size_t)NN * NCLS * 4);
  float*    Db0    = (float*)carve(p, (size_t)NN * NCLS * 4);
  float*    Db1    = (float*)carve(p, (size_t)NN * NCLS * 4);
  _Float16* H0     = (_Float16*)carve(p, (size_t)NN * NCLS * 2);
  _Float16* H1     = (_Float16*)carve(p, (size_t)NN * NCLS * 2);

  k_prep<<<NN, DD, 0, stream>>>(emb, sigma, ehi, elo, sq);
  k_gemmw<<<dim3(NN / 128, NN / 128), 256, 0, stream>>>(ehi, elo, sq, Wm);
  k_zero<<<(NN * 128 + 255) / 256, 256, 0, stream>>>(mask, NN * 128);
  k_topk<<<NN, 256, 0, stream>>>(Wm, topk, kptr);
  k_scatter<<<(NN * KMAX + 255) / 256, 256, 0, stream>>>(topk, mask, kptr);
  k_degree<<<NN, 128, 0, stream>>>(mask, Wm, Dinv, deg);
  k_scan<<<1, 256, 0, stream>>>(deg, rowptr);
  k_fill<<<NN, 128, 0, stream>>>(mask, Wm, Dinv, rowptr, cv, alphap);
  k_taskrow<<<(MAXTASK + 255) / 256, 256, 0, stream>>>(rowptr, trow);

  k_init_state<<<(NN * NCLS) / 256, 256, 0, stream>>>(labels, Ns, X, Rbuf, Db0,
                                                      H0, SV);
  for (int it = 0; it < NITER; ++it) {
    float*    Dc = (it & 1) ? Db1 : Db0;
    float*    Dn = (it & 1) ? Db0 : Db1;
    _Float16* Hc = (it & 1) ? H1 : H0;
    _Float16* Hn = (it & 1) ? H0 : H1;
    k_spmm<<<1280, 256, 0, stream>>>(rowptr, cv, trow, Hc, SV);
    k_update<<<(NN * NCLS) / 512, 256, 0, stream>>>(X, Rbuf, Dc, Dn, Hn, SV,
                                                    alphap, it);
  }
}

// Round 17
// 960.362 us; speedup vs baseline: 9.6265x; 1.2067x over previous
//
#include <hip/hip_runtime.h>
#include <math.h>

#define NN 4096
#define DD 256
#define NCLS 64
#define EPSF 2.2204460492503131e-16f
#define NITER 32
#define KMAX 64
#define TASK 32                      // nnz per wave-task
#define NNZ_CAP (NN * 2 * KMAX)
#define MAXTASK (NNZ_CAP / TASK)
#define LDP 40                       // padded LDS row (halves): 80B stride

typedef __attribute__((ext_vector_type(8))) _Float16 half8;
typedef __attribute__((ext_vector_type(4))) float f32x4;

// ---- prep: e = emb/(sigma+eps)^2, split into f16 hi/lo, sq = rowsum(e*e) ----
__global__ void k_prep(const float* __restrict__ emb, const float* __restrict__ sig,
                       _Float16* __restrict__ ehi, _Float16* __restrict__ elo,
                       float* __restrict__ sq) {
  int row = blockIdx.x, t = threadIdx.x;  // block = 256 = DD
  float s = sig[row] + EPSF;
  float v = emb[row * DD + t];
  v = v / s; v = v / s;
  _Float16 h = (_Float16)v;
  _Float16 l = (_Float16)(v - (float)h);
  ehi[row * DD + t] = h;
  elo[row * DD + t] = l;
  __shared__ float red[DD];
  red[t] = v * v; __syncthreads();
  for (int off = 128; off > 0; off >>= 1) {
    if (t < off) red[t] += red[t + off];
    __syncthreads();
  }
  if (t == 0) sq[row] = red[0];
}

// ---- dense W = exp(-dist/2) via f16 split MFMA: G = e e^T (C = A.B^T) ------
__global__ __launch_bounds__(256) void k_gemmw(
    const _Float16* __restrict__ ehi, const _Float16* __restrict__ elo,
    const float* __restrict__ sq, float* __restrict__ W) {
  __shared__ _Float16 Ah[128][LDP];
  __shared__ _Float16 Al[128][LDP];
  __shared__ _Float16 Bh[128][LDP];
  __shared__ _Float16 Bl[128][LDP];
  int t = threadIdx.x;
  int lane = t & 63, wv = t >> 6;
  int wm = wv >> 1, wn = wv & 1;
  int rowbase = blockIdx.y * 128, colbase = blockIdx.x * 128;
  f32x4 acc[4][4];
#pragma unroll
  for (int m = 0; m < 4; ++m)
#pragma unroll
    for (int n = 0; n < 4; ++n) acc[m][n] = (f32x4){0.f, 0.f, 0.f, 0.f};
  int fr = lane & 15, kc = (lane >> 4) * 8;
  for (int k0 = 0; k0 < DD; k0 += 32) {
    for (int q = t; q < 512; q += 256) {
      int lr = q >> 2, ls = (q & 3) * 8;
      size_t ga = (size_t)(rowbase + lr) * DD + k0 + ls;
      size_t gb = (size_t)(colbase + lr) * DD + k0 + ls;
      *(uint4*)&Ah[lr][ls] = *(const uint4*)&ehi[ga];
      *(uint4*)&Al[lr][ls] = *(const uint4*)&elo[ga];
      *(uint4*)&Bh[lr][ls] = *(const uint4*)&ehi[gb];
      *(uint4*)&Bl[lr][ls] = *(const uint4*)&elo[gb];
    }
    __syncthreads();
    half8 ah[4], al[4], bh[4], bl[4];
#pragma unroll
    for (int m = 0; m < 4; ++m) {
      ah[m] = *(const half8*)&Ah[wm * 64 + m * 16 + fr][kc];
      al[m] = *(const half8*)&Al[wm * 64 + m * 16 + fr][kc];
    }
#pragma unroll
    for (int n = 0; n < 4; ++n) {
      bh[n] = *(const half8*)&Bh[wn * 64 + n * 16 + fr][kc];
      bl[n] = *(const half8*)&Bl[wn * 64 + n * 16 + fr][kc];
    }
#pragma unroll
    for (int m = 0; m < 4; ++m)
#pragma unroll
      for (int n = 0; n < 4; ++n) {
        acc[m][n] = __builtin_amdgcn_mfma_f32_16x16x32_f16(ah[m], bh[n], acc[m][n], 0, 0, 0);
        acc[m][n] = __builtin_amdgcn_mfma_f32_16x16x32_f16(ah[m], bl[n], acc[m][n], 0, 0, 0);
        acc[m][n] = __builtin_amdgcn_mfma_f32_16x16x32_f16(al[m], bh[n], acc[m][n], 0, 0, 0);
      }
    __syncthreads();
  }
#pragma unroll
  for (int m = 0; m < 4; ++m) {
#pragma unroll
    for (int reg = 0; reg < 4; ++reg) {
      int i = rowbase + wm * 64 + m * 16 + (lane >> 4) * 4 + reg;
      float sqi = sq[i];
#pragma unroll
      for (int n = 0; n < 4; ++n) {
        int j = colbase + wn * 64 + n * 16 + (lane & 15);
        float dist = (sqi + sq[j] - 2.0f * acc[m][n][reg]) * (1.0f / DD);
        W[(size_t)i * NN + j] = expf(-0.5f * dist);
      }
    }
  }
}

// ---------------- zero a u32 buffer ----------------
__global__ void k_zero(unsigned* __restrict__ p, int n) {
  int i = blockIdx.x * blockDim.x + threadIdx.x;
  if (i < n) p[i] = 0u;
}

// ---- per-row top-k (R8 proven): 4 waves x 1024 elems, 16/lane --------------
// ties: higher value wins; equal value -> lower column (matches jax top_k).
__global__ __launch_bounds__(256) void k_topk(const float* __restrict__ W,
                                              int* __restrict__ idx,
                                              const int* __restrict__ kptr) {
  int row = blockIdx.x;
  int t = threadIdx.x, lane = t & 63, w = t >> 6;
  int K = kptr[0]; if (K > KMAX) K = KMAX;
  const float* Wr = &W[(size_t)row * NN];
  float val[16];
#pragma unroll
  for (int i = 0; i < 16; ++i) val[i] = Wr[w * 1024 + i * 64 + lane];
  unsigned rm = 0;
  __shared__ float lv[4][KMAX];
  __shared__ int   lc[4][KMAX];
  for (int k = 0; k < K; ++k) {
    float vb = -1e38f; int cb = 0x7fffffff;
#pragma unroll
    for (int i = 0; i < 16; ++i) {
      bool ok = !((rm >> i) & 1u);
      if (ok && val[i] > vb) { vb = val[i]; cb = w * 1024 + i * 64 + lane; }
    }
    for (int off = 32; off > 0; off >>= 1) {
      float ov = __shfl_xor(vb, off, 64);
      int   oc = __shfl_xor(cb, off, 64);
      if (ov > vb || (ov == vb && oc < cb)) { vb = ov; cb = oc; }
    }
    if ((cb & 63) == lane) { int i = (cb >> 6) & 15; rm |= 1u << i; }
    if (lane == 0) { lv[w][k] = vb; lc[w][k] = cb; }
  }
  __syncthreads();
  if (w == 0) {
    float cv[4]; int cc[4]; unsigned crm = 0;
#pragma unroll
    for (int j = 0; j < 4; ++j) {
      if (lane < K) { cv[j] = lv[j][lane]; cc[j] = lc[j][lane]; }
      else { cv[j] = -1e38f; cc[j] = 0x7fffffff; }
    }
    for (int k = 0; k < K; ++k) {
      float vb = -1e38f; int cb = 0x7fffffff;
#pragma unroll
      for (int j = 0; j < 4; ++j) {
        bool ok = !((crm >> j) & 1u);
        if (ok && (cv[j] > vb || (cv[j] == vb && cc[j] < cb))) { vb = cv[j]; cb = cc[j]; }
      }
      for (int off = 32; off > 0; off >>= 1) {
        float ov = __shfl_xor(vb, off, 64);
        int   oc = __shfl_xor(cb, off, 64);
        if (ov > vb || (ov == vb && oc < cb)) { vb = ov; cb = oc; }
      }
#pragma unroll
      for (int j = 0; j < 4; ++j) if (cc[j] == cb) crm |= 1u << j;
      if (lane == 0) idx[row * KMAX + k] = cb;
    }
  }
}

// ---------------- scatter symmetric bitmask ----------------
__global__ void k_scatter(const int* __restrict__ idx, unsigned* __restrict__ mask,
                          const int* __restrict__ kptr) {
  int K = kptr[0]; if (K > KMAX) K = KMAX;
  int tid = blockIdx.x * blockDim.x + threadIdx.x;
  if (tid >= NN * K) return;
  int i = tid / K, k = tid % K;
  int j = idx[i * KMAX + k];
  atomicOr(&mask[i * 128 + (j >> 5)], 1u << (j & 31));
  atomicOr(&mask[j * 128 + (i >> 5)], 1u << (i & 31));
}

// ---------------- degree (sum of masked W per row) + Dinv ------------
__global__ void k_degree(const unsigned* __restrict__ mask, const float* __restrict__ W,
                         float* __restrict__ Dinv, int* __restrict__ deg) {
  int row = blockIdx.x, t = threadIdx.x;  // block = 128
  unsigned m = mask[row * 128 + t];
  float dsum = 0.f; int cnt = __popc(m);
  unsigned mm = m;
  while (mm) {
    int b = __ffs(mm) - 1; mm &= mm - 1;
    dsum += W[(size_t)row * NN + t * 32 + b];
  }
  __shared__ float rs[128];
  __shared__ int   rc[128];
  rs[t] = dsum; rc[t] = cnt; __syncthreads();
  for (int off = 64; off > 0; off >>= 1) {
    if (t < off) { rs[t] += rs[t + off]; rc[t] += rc[t + off]; }
    __syncthreads();
  }
  if (t == 0) { deg[row] = rc[0]; Dinv[row] = sqrtf(1.0f / (rs[0] + EPSF)); }
}

// ------- exclusive scan of deg -> rowptr (one block, shuffle scan) ----------
__global__ void k_scan(const int* __restrict__ deg, int* __restrict__ rowptr) {
  int t = threadIdx.x;
  int lane = t & 63, w = t >> 6;
  int loc[16]; int s = 0;
  for (int u = 0; u < 16; ++u) { loc[u] = s; s += deg[t * 16 + u]; }
  int tot = s, inc = s;
  for (int off = 1; off < 64; off <<= 1) {
    int n = __shfl_up(inc, off, 64);
    if (lane >= off) inc += n;
  }
  __shared__ int wt[4];
  if (lane == 63) wt[w] = inc;
  __syncthreads();
  int base = 0;
  for (int u = 0; u < w; ++u) base += wt[u];
  int excl = base + inc - tot;
  for (int u = 0; u < 16; ++u) rowptr[t * 16 + u] = excl + loc[u];
  if (t == 255) rowptr[NN] = excl + tot;
}

// ---------------- fill CSR of alpha*S, packed (col, val) --------------------
__global__ void k_fill(const unsigned* __restrict__ mask, const float* __restrict__ W,
                       const float* __restrict__ Dinv, const int* __restrict__ rowptr,
                       int2* __restrict__ cv, const float* __restrict__ alphap) {
  int row = blockIdx.x, t = threadIdx.x;  // block = 128
  float alpha = alphap[0];
  unsigned m = mask[row * 128 + t];
  __shared__ int wcnt[128];
  wcnt[t] = __popc(m); __syncthreads();
  int pre = 0;
  for (int u = 0; u < t; ++u) pre += wcnt[u];
  int base = rowptr[row] + pre;
  float di = Dinv[row];
  while (m) {
    int b = __ffs(m) - 1; m &= m - 1;
    int j = t * 32 + b;
    float v = alpha * W[(size_t)row * NN + j] * di * Dinv[j];
    cv[base] = make_int2(j, __float_as_int(v));
    ++base;
  }
}

// ------- precompute task -> starting row ------
__global__ void k_taskrow(const int* __restrict__ rowptr, int* __restrict__ taskrow) {
  int task = blockIdx.x * blockDim.x + threadIdx.x;
  int nnz = rowptr[NN];
  int ntask = (nnz + TASK - 1) / TASK;
  if (task >= ntask) return;
  int start = task * TASK;
  int lo = 0, hi = NN;
  while (hi - lo > 1) {
    int mid = (lo + hi) >> 1;
    if (rowptr[mid] <= start) lo = mid; else hi = mid;
  }
  taskrow[task] = lo;
}

// ---- init: X=0, R=D0=B, SV=0 ----------------------------------------------
__global__ __launch_bounds__(256) void k_init_state(
    const int* __restrict__ labels, int Ns, float* __restrict__ X,
    float* __restrict__ R, float* __restrict__ D0, float* __restrict__ SV) {
  int idx = blockIdx.x * 256 + threadIdx.x;     // NN*64 total
  int i = idx >> 6, c = idx & 63;
  float b = (i < Ns && labels[i] == c) ? 1.0f : 0.0f;
  X[idx] = 0.0f; R[idx] = b; D0[idx] = b; SV[idx] = 0.0f;
}

// ------- pass 1: SV += (alpha*S) @ D, f32 gather, 1 task/wave ---------------
__global__ __launch_bounds__(256) void k_spmm(
    const int* __restrict__ rowptr, const int2* __restrict__ cv,
    const int* __restrict__ taskrow, const float* __restrict__ Dc,
    float* __restrict__ SV) {
  int lane = threadIdx.x & 63;
  int wave0 = (blockIdx.x * 256 + threadIdx.x) >> 6;
  int nwaves = (gridDim.x * 256) >> 6;
  int nnz = rowptr[NN];
  int ntask = (nnz + TASK - 1) / TASK;
  for (int task = wave0; task < ntask; task += nwaves) {
    int start = task * TASK;
    int end = start + TASK; if (end > nnz) end = nnz;
    float prod[TASK];
#pragma unroll
    for (int u = 0; u < TASK; ++u) {
      int p = start + u;
      if (p < end) {
        int2 c = cv[p];
        prod[u] = __int_as_float(c.y) * Dc[(size_t)c.x * 64 + lane];
      } else prod[u] = 0.0f;
    }
    int r = taskrow[task];
    int rend = rowptr[r + 1];
    float acc = 0.0f;
#pragma unroll
    for (int u = 0; u < TASK; ++u) {
      int p = start + u;
      if (p >= end) break;
      while (p >= rend) {
        atomicAdd(&SV[(size_t)r * 64 + lane], acc);
        acc = 0.0f; ++r; rend = rowptr[r + 1];
      }
      acc += prod[u];
    }
    atomicAdd(&SV[(size_t)r * 64 + lane], acc);
  }
}

// ------- pass 2: Chebyshev update (float2 streaming), re-zeros SV -----------
__global__ __launch_bounds__(256) void k_update(
    float* __restrict__ X, float* __restrict__ R, const float* __restrict__ Dcur,
    float* __restrict__ Dnxt, float* __restrict__ SV,
    const float* __restrict__ alphap, int it) {
  int idx = (blockIdx.x * 256 + threadIdx.x) * 2;   // grid = NN*64/512 blocks
  float alpha = alphap[0];
  float sigma1 = 1.0f / alpha;
  float rho_prev = alpha;
  for (int k = 0; k < it; ++k) rho_prev = 1.0f / (2.0f * sigma1 - rho_prev);
  float rho = 1.0f / (2.0f * sigma1 - rho_prev);
  float c1 = rho * rho_prev, c2 = 2.0f * rho / alpha;
  float2 s = *(float2*)&SV[idx];
  *(float2*)&SV[idx] = make_float2(0.f, 0.f);
  float2 d = *(const float2*)&Dcur[idx];
  float2 x = *(float2*)&X[idx];
  float2 r = *(float2*)&R[idx];
  x.x += d.x; x.y += d.y;
  r.x -= (d.x - s.x); r.y -= (d.y - s.y);
  float2 dn;
  dn.x = c1 * d.x + c2 * r.x; dn.y = c1 * d.y + c2 * r.y;
  *(float2*)&X[idx] = x;
  *(float2*)&R[idx] = r;
  *(float2*)&Dnxt[idx] = dn;
}

// ---------------- host launch ----------------
static inline char* carve(char*& p, size_t bytes) {
  char* r = p;
  size_t a = (bytes + 255) & ~(size_t)255;
  p += a;
  return r;
}

extern "C" void kernel_launch(void* const* d_in, const int* in_sizes, int n_in,
                              void* d_out, int out_size, void* d_ws, size_t ws_size,
                              hipStream_t stream) {
  const float* emb    = (const float*)d_in[0];
  const float* sigma  = (const float*)d_in[1];
  const float* alphap = (const float*)d_in[2];
  const int*   labels = (const int*)d_in[3];
  const int*   kptr   = (const int*)d_in[4];
  int Ns = in_sizes[3];
  float* X = (float*)d_out;   // X state IS the output [NN][64]

  char* p = (char*)d_ws;
  _Float16* ehi    = (_Float16*)carve(p, (size_t)NN * DD * 2);
  _Float16* elo    = (_Float16*)carve(p, (size_t)NN * DD * 2);
  float*    sq     = (float*)carve(p, NN * 4);
  float*    Wm     = (float*)carve(p, (size_t)NN * NN * 4);
  int*      topk   = (int*)carve(p, NN * KMAX * 4);
  unsigned* mask   = (unsigned*)carve(p, NN * 128 * 4);
  float*    Dinv   = (float*)carve(p, NN * 4);
  int*      deg    = (int*)carve(p, NN * 4);
  int*      rowptr = (int*)carve(p, (NN + 1) * 4);
  int2*     cv     = (int2*)carve(p, (size_t)NNZ_CAP * 8);
  int*      trow   = (int*)carve(p, (size_t)MAXTASK * 4);
  float*    Rbuf   = (float*)carve(p, (size_t)NN * NCLS * 4);
  float*    SV     = (float*)carve(p, (size_t)NN * NCLS * 4);
  float*    Db0    = (float*)carve(p, (size_t)NN * NCLS * 4);
  float*    Db1    = (float*)carve(p, (size_t)NN * NCLS * 4);

  k_prep<<<NN, DD, 0, stream>>>(emb, sigma, ehi, elo, sq);
  k_gemmw<<<dim3(NN / 128, NN / 128), 256, 0, stream>>>(ehi, elo, sq, Wm);
  k_zero<<<(NN * 128 + 255) / 256, 256, 0, stream>>>(mask, NN * 128);
  k_topk<<<NN, 256, 0, stream>>>(Wm, topk, kptr);
  k_scatter<<<(NN * KMAX + 255) / 256, 256, 0, stream>>>(topk, mask, kptr);
  k_degree<<<NN, 128, 0, stream>>>(mask, Wm, Dinv, deg);
  k_scan<<<1, 256, 0, stream>>>(deg, rowptr);
  k_fill<<<NN, 128, 0, stream>>>(mask, Wm, Dinv, rowptr, cv, alphap);
  k_taskrow<<<(MAXTASK + 255) / 256, 256, 0, stream>>>(rowptr, trow);

  k_init_state<<<(NN * NCLS) / 256, 256, 0, stream>>>(labels, Ns, X, Rbuf, Db0, SV);
  for (int it = 0; it < NITER; ++it) {
    float* Dc = (it & 1) ? Db1 : Db0;
    float* Dn = (it & 1) ? Db0 : Db1;
    k_spmm<<<1280, 256, 0, stream>>>(rowptr, cv, trow, Dc, SV);
    k_update<<<(NN * NCLS) / 512, 256, 0, stream>>>(X, Rbuf, Dc, Dn, SV, alphap, it);
  }
}